// Round 8
// baseline (85.963 us; speedup 1.0000x reference)
//
#include <hip/hip_runtime.h>
#include <cstdint>
#include <cstddef>

#define BB 16
#define AA 8400
#define CC 80
#define MM 32
#define TOPK 13
#define CAPR 1600            // slots per (b,m) row: [0,64) fixed + appends
#define APPEND_MAX (CAPR - 64)

// Shared CIoU (clipped) so every use site has the identical formula.
__device__ __forceinline__ float ciou_clip(
    float gx1, float gy1, float gx2, float gy2, float at1,
    float4 pb, float w2, float h2, float at2)
{
  const float w1 = gx2 - gx1, h1 = gy2 - gy1 + 1e-7f;
  const float iw = fmaxf(fminf(gx2, pb.z) - fmaxf(gx1, pb.x), 0.f);
  const float ih = fmaxf(fminf(gy2, pb.w) - fmaxf(gy1, pb.y), 0.f);
  const float inter = iw * ih;
  const float uni = w1*h1 + w2*h2 - inter + 1e-7f;
  const float iou = inter / uni;
  const float cw = fmaxf(gx2, pb.z) - fminf(gx1, pb.x);
  const float ch = fmaxf(gy2, pb.w) - fminf(gy1, pb.y);
  const float c2 = cw*cw + ch*ch + 1e-7f;
  const float rx = pb.x + pb.z - gx1 - gx2;
  const float ry = pb.y + pb.w - gy1 - gy2;
  const float rho2 = (rx*rx + ry*ry) * 0.25f;
  const float dv = at2 - at1;
  const float v = 0.4052847345693511f * dv * dv;
  const float alpha = v / (v - iou + (1.f + 1e-7f));
  return fmaxf(iou - (rho2 / c2 + v * alpha), 0.f);
}

// ---------------------------------------------------------------------------
// K0: zero the append counters (must precede k_cand; tiny dedicated kernel —
// hipMemsetAsync's fill kernel costs ~40us at small sizes).
// ---------------------------------------------------------------------------
__global__ void k_init(unsigned int* __restrict__ cnts)
{
  if (threadIdx.x < BB*MM) cnts[threadIdx.x] = 0u;
}

// ---------------------------------------------------------------------------
// K1: per-(b,a) candidate generation (loop-flipped).
// Thread (b,a): 32-box mind-test from LDS -> inmask; CIoU+score only for set
// bits; val>0 appended to per-(b,m) list (atomicAdd slot). Slots [0,64) of
// each row are the always-written first-64 full evals (exact zero-tie
// candidates: a row with <13 positives zero-fills from indices < 64).
// Append order is nondeterministic but the SET is deterministic; p2 uses
// full (val,idx) comparisons so the final top-13 is order-independent.
// Masked gts get boxes poisoned to (+1e30,..,-1e30) -> mind test fails.
// ---------------------------------------------------------------------------
__global__ __launch_bounds__(256) void k_cand(
    const float* __restrict__ pred_cls, const float* __restrict__ pred_bbox,
    const float* __restrict__ anchors, const int* __restrict__ gt_cls,
    const float* __restrict__ gt_bbox, const float* __restrict__ mask_gt,
    unsigned int* __restrict__ cnts, uint2* __restrict__ entries,
    unsigned int* __restrict__ claim,
    unsigned int* __restrict__ pos_align, unsigned int* __restrict__ pos_ovl)
{
  const int b = blockIdx.y;
  __shared__ float4 s_mb[MM];   // mask-adjusted boxes (in-test)
  __shared__ float4 s_gb[MM];   // original boxes (eval)
  __shared__ float  s_at[MM];
  __shared__ int    s_lbl[MM];
  if (threadIdx.x < MM) {
    const int m = threadIdx.x;
    const float4 g = reinterpret_cast<const float4*>(gt_bbox)[b*MM + m];
    s_gb[m] = g;
    s_at[m] = atanf((g.z - g.x) / (g.w - g.y + 1e-7f));
    s_lbl[m] = gt_cls[b*MM + m];
    const bool on = mask_gt[b*MM + m] > 0.f;
    s_mb[m] = on ? g : make_float4(1e30f, 1e30f, -1e30f, -1e30f);
    if (blockIdx.x == 0) { pos_align[b*MM + m] = 0u; pos_ovl[b*MM + m] = 0u; }
  }
  __syncthreads();
  const int a = blockIdx.x*256 + threadIdx.x;
  if (a >= AA) return;
  claim[b*AA + a] = 0u;          // zero-init duty (replaces memset)

  const float2 xy = reinterpret_cast<const float2*>(anchors)[a];
  unsigned inmask = 0u;
  #pragma unroll
  for (int m = 0; m < MM; ++m) {
    const float4 g = s_mb[m];
    const float mind = fminf(fminf(xy.x - g.x, xy.y - g.y),
                             fminf(g.z - xy.x, g.w - xy.y));
    inmask |= (mind > 1e-9f) ? (1u << m) : 0u;
  }

  float4 pb = make_float4(0.f,0.f,0.f,0.f);
  float w2 = 0.f, h2 = 1.f, at2 = 0.f;
  if (inmask != 0u || a < 64) {
    pb = reinterpret_cast<const float4*>(pred_bbox)[b*AA + a];
    w2 = pb.z - pb.x; h2 = pb.w - pb.y + 1e-7f;
    at2 = atanf(w2 / h2);
  }
  const float* clsrow = pred_cls + (size_t)(b*AA + a)*CC;

  if (a < 64) {
    // fixed region: slot a of every unmasked row (val==0 when out-of-gts,
    // exactly matching the reference's zero align entries)
    for (int m = 0; m < MM; ++m) {
      if (s_mb[m].x > 1e29f) continue;         // masked gt: row never read
      float val = 0.f;
      if (inmask & (1u << m)) {
        const float4 g = s_gb[m];
        const float ov = ciou_clip(g.x, g.y, g.z, g.w, s_at[m], pb, w2, h2, at2);
        const float o2 = ov * ov;
        val = clsrow[s_lbl[m]] * (o2 * o2 * o2);   // score * ov^6
      }
      entries[(size_t)(b*MM + m)*CAPR + a] =
          make_uint2(__float_as_uint(val), (unsigned)a);
    }
  } else {
    unsigned msk = inmask;
    while (msk) {
      const int m = __ffs(msk) - 1; msk &= msk - 1u;
      const float4 g = s_gb[m];
      const float ov = ciou_clip(g.x, g.y, g.z, g.w, s_at[m], pb, w2, h2, at2);
      const float o2 = ov * ov;
      const float val = clsrow[s_lbl[m]] * (o2 * o2 * o2);
      if (val > 0.f) {   // zero-valued a>=64 always loses to first-64 zeros
        const unsigned pos = atomicAdd(&cnts[b*MM + m], 1u);
        if (pos < APPEND_MAX)
          entries[(size_t)(b*MM + m)*CAPR + 64 + pos] =
              make_uint2(__float_as_uint(val), (unsigned)a);
      }
    }
  }
}

// ---------------------------------------------------------------------------
// K2: per-(b,m) top-13 over the candidate list with FULL (val desc, idx asc)
// tie comparisons (order-independent => exact jax.lax.top_k semantics), then
// mask_in_gts check + claim-bit atomicOr. 4 rows per 256-thread block.
// ---------------------------------------------------------------------------
__global__ __launch_bounds__(256) void k_topk_p2(
    const unsigned int* __restrict__ cnts, const uint2* __restrict__ entries,
    const float* __restrict__ anchors, const float* __restrict__ gt_bbox,
    const float* __restrict__ mask_gt, unsigned int* __restrict__ claim)
{
  const int wave = threadIdx.x >> 6, lane = threadIdx.x & 63;
  const int m = blockIdx.x*4 + wave, b = blockIdx.y;
  if (mask_gt[b*MM + m] <= 0.f) return;
  const int row = b*MM + m;
  const uint2* e = entries + (size_t)row * CAPR;
  int nap = (int)cnts[row]; if (nap > APPEND_MAX) nap = APPEND_MAX;
  const int n = 64 + nap;

  float v[TOPK]; int id[TOPK];
  #pragma unroll
  for (int i = 0; i < TOPK; ++i) { v[i] = -1.f; id[i] = 0x7fffffff; }

  for (int k = lane; k < n; k += 64) {
    const uint2 c = e[k];
    const float val = __uint_as_float(c.x);
    const int a = (int)c.y;
    if (val > v[TOPK-1] || (val == v[TOPK-1] && a < id[TOPK-1])) {
      #pragma unroll
      for (int i = TOPK-1; i >= 1; --i) {     // static-index shift network
        const bool ci = (val > v[i])   || (val == v[i]   && a < id[i]);
        const bool cp = (val > v[i-1]) || (val == v[i-1] && a < id[i-1]);
        if (ci) {
          if (cp) { v[i] = v[i-1]; id[i] = id[i-1]; }
          else    { v[i] = val;    id[i] = a; }
        }
      }
      if ((val > v[0]) || (val == v[0] && a < id[0])) { v[0] = val; id[0] = a; }
    }
  }

  const float4 gb = reinterpret_cast<const float4*>(gt_bbox)[b*MM + m];
  const unsigned int bit = 1u << m;

  for (int r = 0; r < TOPK; ++r) {
    float bv = v[0]; int bi = id[0];
    #pragma unroll
    for (int off = 32; off; off >>= 1) {
      const float ovv = __shfl_xor(bv, off);
      const int   oii = __shfl_xor(bi, off);
      if (ovv > bv || (ovv == bv && oii < bi)) { bv = ovv; bi = oii; }
    }
    if (v[0] == bv && id[0] == bi) {        // unique winner pops its head
      #pragma unroll
      for (int i = 0; i < TOPK-1; ++i) { v[i] = v[i+1]; id[i] = id[i+1]; }
      v[TOPK-1] = -1.f; id[TOPK-1] = 0x7fffffff;
    }
    if (lane == 0 && bi < AA) {
      const float2 xy = reinterpret_cast<const float2*>(anchors)[bi];
      const float mind = fminf(fminf(xy.x - gb.x, xy.y - gb.y),
                               fminf(gb.z - xy.x, gb.w - xy.y));
      if (mind > 1e-9f) atomicOr(&claim[b*AA + bi], bit);
    }
  }
}

// ---------------------------------------------------------------------------
// K3: per-anchor resolution with sparse CIoU recompute. fg==1 -> claiming m;
// fg>1 -> first-max argmax_m of masked overlaps (recomputed). Writes
// target_bbox + fg_mask + anchor_m/al; atomicMax pos_align/pos_ovl.
// ---------------------------------------------------------------------------
__global__ __launch_bounds__(256) void k_resolve(
    const float* __restrict__ pred_cls, const float* __restrict__ pred_bbox,
    const float* __restrict__ anchors, const int* __restrict__ gt_cls,
    const float* __restrict__ gt_bbox, const float* __restrict__ mask_gt,
    const unsigned int* __restrict__ claim,
    float* __restrict__ out_bbox, float* __restrict__ out_fg,
    int* __restrict__ anchor_m, float* __restrict__ anchor_al,
    unsigned int* __restrict__ pos_align, unsigned int* __restrict__ pos_ovl)
{
  const int b = blockIdx.y;
  __shared__ float s_x1[MM], s_y1[MM], s_x2[MM], s_y2[MM], s_at[MM], s_mgt[MM];
  __shared__ int s_lbl[MM];
  if (threadIdx.x < MM) {
    int m = threadIdx.x;
    float4 g = reinterpret_cast<const float4*>(gt_bbox)[b*MM + m];
    s_x1[m] = g.x; s_y1[m] = g.y; s_x2[m] = g.z; s_y2[m] = g.w;
    s_at[m] = atanf((g.z - g.x) / (g.w - g.y + 1e-7f));
    s_lbl[m] = gt_cls[b*MM + m];
    s_mgt[m] = mask_gt[b*MM + m];
  }
  __syncthreads();
  const int a = blockIdx.x*256 + threadIdx.x;
  if (a >= AA) return;
  const unsigned int cb = claim[b*AA + a];
  const int fg = __popc(cb);
  int asg = -1; float bestov = 0.f;
  if (fg > 0) {
    const float4 pb = reinterpret_cast<const float4*>(pred_bbox)[b*AA + a];
    const float2 xy = reinterpret_cast<const float2*>(anchors)[a];
    const float w2 = pb.z - pb.x, h2 = pb.w - pb.y + 1e-7f;
    const float at2 = atanf(w2 / h2);
    if (fg == 1) {
      asg = __ffs(cb) - 1;   // claimed => in-gts && mask_gt>0 already hold
      bestov = ciou_clip(s_x1[asg], s_y1[asg], s_x2[asg], s_y2[asg], s_at[asg],
                         pb, w2, h2, at2);
    } else {
      // is_max: first argmax over ALL m of masked overlaps
      float best = -1.f; int bm = 0;
      for (int m = 0; m < MM; ++m) {
        float ov = 0.f;
        const float mind = fminf(fminf(xy.x - s_x1[m], xy.y - s_y1[m]),
                                 fminf(s_x2[m] - xy.x, s_y2[m] - xy.y));
        if (mind > 1e-9f && s_mgt[m] > 0.f)
          ov = ciou_clip(s_x1[m], s_y1[m], s_x2[m], s_y2[m], s_at[m],
                         pb, w2, h2, at2);
        if (ov > best) { best = ov; bm = m; }   // strict > => first max
      }
      asg = bm; bestov = best;
    }
  }
  const int tgt = (asg >= 0) ? asg : 0;   // argmax of all-zero column = 0
  float4 tb; tb.x = s_x1[tgt]; tb.y = s_y1[tgt]; tb.z = s_x2[tgt]; tb.w = s_y2[tgt];
  reinterpret_cast<float4*>(out_bbox)[b*AA + a] = tb;
  out_fg[b*AA + a] = (asg >= 0) ? 1.f : 0.f;
  anchor_m[b*AA + a] = asg;
  float av = 0.f;
  if (asg >= 0) {
    const float o2 = bestov * bestov;
    av = pred_cls[(size_t)(b*AA + a)*CC + s_lbl[asg]] * (o2 * o2 * o2);
    atomicMax(&pos_align[b*MM + asg], __float_as_uint(av));    // >=0 floats
    atomicMax(&pos_ovl[b*MM + asg], __float_as_uint(bestov));
  }
  anchor_al[b*AA + a] = av;
}

// ---------------------------------------------------------------------------
// K4: target_cls (B,A,C) float4-coalesced: norm at the label slot, else 0.
// ---------------------------------------------------------------------------
__global__ __launch_bounds__(256) void k_cls(
    const int* __restrict__ anchor_m, const float* __restrict__ anchor_al,
    const unsigned int* __restrict__ pos_align, const unsigned int* __restrict__ pos_ovl,
    const int* __restrict__ gt_cls, float* __restrict__ out_cls)
{
  const int tid = blockIdx.x*256 + threadIdx.x;
  if (tid >= BB*AA*(CC/4)) return;
  const int q  = tid % (CC/4);
  const int ba = tid / (CC/4);
  const int b  = ba / AA;
  const int m  = anchor_m[ba];
  float4 o = make_float4(0.f, 0.f, 0.f, 0.f);
  if (m >= 0) {
    const float pa = __uint_as_float(pos_align[b*MM + m]);
    const float po = __uint_as_float(pos_ovl[b*MM + m]);
    const float norm = anchor_al[ba] * po / (pa + 1e-9f);
    const int lbl = gt_cls[b*MM + m];
    const int c0 = q * 4;
    if (lbl == c0    ) o.x = norm;
    if (lbl == c0 + 1) o.y = norm;
    if (lbl == c0 + 2) o.z = norm;
    if (lbl == c0 + 3) o.w = norm;
  }
  reinterpret_cast<float4*>(out_cls)[tid] = o;
}

// ---------------------------------------------------------------------------
extern "C" void kernel_launch(void* const* d_in, const int* in_sizes, int n_in,
                              void* d_out, int out_size, void* d_ws, size_t ws_size,
                              hipStream_t stream)
{
  const float* pred_cls  = (const float*)d_in[0];
  const float* pred_bbox = (const float*)d_in[1];
  const float* anchors   = (const float*)d_in[2];
  const int*   gt_cls    = (const int*)  d_in[3];
  const float* gt_bbox   = (const float*)d_in[4];
  const float* mask_gt   = (const float*)d_in[5];

  // ws layout:
  //   claim      : B*A u32             @ 0          (537600 B)
  //   pos_align  : B*M u32(float)      @ 537600     (2048 B)
  //   pos_ovl    : B*M u32(float)      @ 539648     (2048 B)
  //   anchor_m   : B*A i32             @ 541696     (537600 B)
  //   anchor_al  : B*A f32             @ 1079296    (537600 B)
  //   cnts       : B*M u32             @ 1616896    (2048 B)
  //   entries    : B*M*CAPR uint2      @ 1618944    (6553600 B)
  // total 8172544 B (~7.8 MB)
  char* ws = (char*)d_ws;
  unsigned int* claim     = (unsigned int*)(ws);
  unsigned int* pos_align = (unsigned int*)(ws + 537600);
  unsigned int* pos_ovl   = (unsigned int*)(ws + 539648);
  int*   anchor_m  = (int*)  (ws + 541696);
  float* anchor_al = (float*)(ws + 1079296);
  unsigned int* cnts = (unsigned int*)(ws + 1616896);
  uint2* entries     = (uint2*)(ws + 1618944);

  float* out_cls  = (float*)d_out;
  float* out_bbox = out_cls + (size_t)BB*AA*CC;
  float* out_fg   = out_bbox + (size_t)BB*AA*4;

  k_init<<<1, 512, 0, stream>>>(cnts);
  k_cand<<<dim3((AA + 255)/256, BB), 256, 0, stream>>>(
      pred_cls, pred_bbox, anchors, gt_cls, gt_bbox, mask_gt,
      cnts, entries, claim, pos_align, pos_ovl);
  k_topk_p2<<<dim3(MM/4, BB), 256, 0, stream>>>(
      cnts, entries, anchors, gt_bbox, mask_gt, claim);
  k_resolve<<<dim3((AA + 255)/256, BB), 256, 0, stream>>>(
      pred_cls, pred_bbox, anchors, gt_cls, gt_bbox, mask_gt, claim,
      out_bbox, out_fg, anchor_m, anchor_al, pos_align, pos_ovl);
  k_cls<<<(BB*AA*(CC/4) + 255)/256, 256, 0, stream>>>(
      anchor_m, anchor_al, pos_align, pos_ovl, gt_cls, out_cls);
}

// Round 9
// 55.738 us; speedup vs baseline: 1.5423x; 1.5423x over previous
//
#include <hip/hip_runtime.h>
#include <cstdint>
#include <cstddef>

#define BB 16
#define AA 8400
#define CC 80
#define MM 32
#define TOPK 13
#define NW 4                 // waves (chunks) per row-block
#define WORDS 264            // u32 words per (b,m) row (8448 bits >= AA)
#define CWORDS 66            // words per chunk
#define CANCH (CWORDS * 32)  // 2112 anchors per chunk

// Shared CIoU (clipped) so every use site has the identical formula.
__device__ __forceinline__ float ciou_clip(
    float gx1, float gy1, float gx2, float gy2, float at1,
    float4 pb, float w2, float h2, float at2)
{
  const float w1 = gx2 - gx1, h1 = gy2 - gy1 + 1e-7f;
  const float iw = fmaxf(fminf(gx2, pb.z) - fmaxf(gx1, pb.x), 0.f);
  const float ih = fmaxf(fminf(gy2, pb.w) - fmaxf(gy1, pb.y), 0.f);
  const float inter = iw * ih;
  const float uni = w1*h1 + w2*h2 - inter + 1e-7f;
  const float iou = inter / uni;
  const float cw = fmaxf(gx2, pb.z) - fminf(gx1, pb.x);
  const float ch = fmaxf(gy2, pb.w) - fminf(gy1, pb.y);
  const float c2 = cw*cw + ch*ch + 1e-7f;
  const float rx = pb.x + pb.z - gx1 - gx2;
  const float ry = pb.y + pb.w - gy1 - gy2;
  const float rho2 = (rx*rx + ry*ry) * 0.25f;
  const float dv = at2 - at1;
  const float v = 0.4052847345693511f * dv * dv;
  const float alpha = v / (v - iou + (1.f + 1e-7f));
  return fmaxf(iou - (rho2 / c2 + v * alpha), 0.f);
}

// ---------------------------------------------------------------------------
// K0: transposed in-gts bitmask via per-m ballots (atomic-free), plus
// claim/pos_* zero-init. Thread (b,a); wave covers 64 consecutive a = 2 words.
// Masked gts are poisoned so their rows come out all-zero.
// ---------------------------------------------------------------------------
__global__ __launch_bounds__(256) void k_mask(
    const float* __restrict__ anchors, const float* __restrict__ gt_bbox,
    const float* __restrict__ mask_gt, unsigned int* __restrict__ inmaskT,
    unsigned int* __restrict__ claim,
    unsigned int* __restrict__ pos_align, unsigned int* __restrict__ pos_ovl)
{
  const int b = blockIdx.y;
  __shared__ float4 s_mb[MM];
  if (threadIdx.x < MM) {
    const int m = threadIdx.x;
    const float4 g = reinterpret_cast<const float4*>(gt_bbox)[b*MM + m];
    s_mb[m] = (mask_gt[b*MM + m] > 0.f) ? g
              : make_float4(1e30f, 1e30f, -1e30f, -1e30f);
    if (blockIdx.x == 0) { pos_align[b*MM + m] = 0u; pos_ovl[b*MM + m] = 0u; }
  }
  __syncthreads();
  const int a = blockIdx.x*256 + threadIdx.x;
  const int wave = threadIdx.x >> 6, lane = threadIdx.x & 63;
  float2 xy = make_float2(-1e30f, -1e30f);      // a>=AA lanes: always fail
  if (a < AA) {
    xy = reinterpret_cast<const float2*>(anchors)[a];
    claim[b*AA + a] = 0u;                       // zero-init (replaces memset)
  }
  const int wslot = blockIdx.x*8 + wave*2;      // first of this wave's 2 words
  #pragma unroll
  for (int m = 0; m < MM; ++m) {
    const float4 g = s_mb[m];
    const float mind = fminf(fminf(xy.x - g.x, xy.y - g.y),
                             fminf(g.z - xy.x, g.w - xy.y));
    const unsigned long long bal = __ballot(mind > 1e-9f);
    unsigned int* wp = inmaskT + (size_t)(b*MM + m)*WORDS + wslot;
    if (lane == 0) wp[0] = (unsigned int)(bal & 0xffffffffull);
    if (lane == 1) wp[1] = (unsigned int)(bal >> 32);
  }
}

// ---------------------------------------------------------------------------
// K1: one block per (b,m) row; 4 waves, each owns a 66-word (2112-anchor)
// chunk: bit-scan -> LDS queue (prefix-compacted, provably fits), dense CIoU
// eval of queue only, per-lane top-13 (full val/idx tie compares ->
// order-independent), 13-round butterfly per wave -> LDS, wave-0 merge of
// 4x13 -> exact row top-13 -> in-gts check + claim atomicOr.
// Zero-tie fill exactness: wave 0 seeds anchors [0,64) with full evals
// (val==0 when out-of-gts) and zeroes queue words 0-1 (covered by seed);
// a row with <13 positives zero-fills from indices <64 (>=51 zeros there),
// ties resolved by ascending index — matches jax.lax.top_k exactly.
// ---------------------------------------------------------------------------
__global__ __launch_bounds__(256) void k_topk(
    const float* __restrict__ pred_cls, const float* __restrict__ pred_bbox,
    const float* __restrict__ anchors, const int* __restrict__ gt_cls,
    const float* __restrict__ gt_bbox, const float* __restrict__ mask_gt,
    const unsigned int* __restrict__ inmaskT, unsigned int* __restrict__ claim)
{
  const int m = blockIdx.x, b = blockIdx.y;
  if (mask_gt[b*MM + m] <= 0.f) return;   // uniform per block
  const int wave = threadIdx.x >> 6, lane = threadIdx.x & 63;
  __shared__ unsigned short q[NW][CANCH];
  __shared__ uint2 s_top[NW][TOPK];

  const float4 gb = reinterpret_cast<const float4*>(gt_bbox)[b*MM + m];
  const float at1 = atanf((gb.z - gb.x) / (gb.w - gb.y + 1e-7f));
  const int lbl = gt_cls[b*MM + m];
  const float*  clsbase = pred_cls + (size_t)b*AA*CC;
  const float4* pbase   = reinterpret_cast<const float4*>(pred_bbox) + (size_t)b*AA;
  const float2* axy     = reinterpret_cast<const float2*>(anchors);

  float v[TOPK]; int id[TOPK];
  #pragma unroll
  for (int i = 0; i < TOPK; ++i) { v[i] = -1.f; id[i] = 0x7fffffff; }

  // wave-0 seed: full eval of anchor a = lane (always a candidate)
  if (wave == 0) {
    const int a = lane;
    const float2 xy = axy[a];
    const float mind = fminf(fminf(xy.x - gb.x, xy.y - gb.y),
                             fminf(gb.z - xy.x, gb.w - xy.y));
    float val = 0.f;
    if (mind > 1e-9f) {
      const float4 pb = pbase[a];
      const float w2 = pb.z - pb.x, h2 = pb.w - pb.y + 1e-7f;
      const float at2 = atanf(w2 / h2);
      const float ov = ciou_clip(gb.x, gb.y, gb.z, gb.w, at1, pb, w2, h2, at2);
      const float o2 = ov * ov;
      val = clsbase[(size_t)a*CC + lbl] * (o2 * o2 * o2);
    }
    v[0] = val; id[0] = a;
  }

  // bit-scan chunk -> queue (ascending anchor order preserved)
  const unsigned int* wrow = inmaskT + (size_t)(b*MM + m)*WORDS + wave*CWORDS;
  int qc = 0;
  #pragma unroll
  for (int it = 0; it < 2; ++it) {
    const int wi = it*64 + lane;
    unsigned int w = 0u;
    if (wi < CWORDS) w = wrow[wi];
    if (wave == 0 && wi < 2) w = 0u;        // a<64 covered by seed
    const int cnt = __popc(w);
    int incl = cnt;
    #pragma unroll
    for (int off = 1; off < 64; off <<= 1) {
      const int t = __shfl_up(incl, off);
      if (lane >= off) incl += t;
    }
    int pos = qc + incl - cnt;
    const int abase = wave*CANCH + wi*32;
    unsigned int t = w;
    while (t) {
      const int bit = __ffs((int)t) - 1; t &= t - 1u;
      q[wave][pos++] = (unsigned short)(abase + bit);
    }
    qc += __shfl(incl, 63);
  }

  // dense eval of queue (per-lane stream is ascending in a)
  for (int k = lane; k < qc; k += 64) {
    const int a = (int)q[wave][k];
    const float4 pb = pbase[a];
    const float w2 = pb.z - pb.x, h2 = pb.w - pb.y + 1e-7f;
    const float at2 = atanf(w2 / h2);
    const float ov = ciou_clip(gb.x, gb.y, gb.z, gb.w, at1, pb, w2, h2, at2);
    const float o2 = ov * ov;
    const float val = clsbase[(size_t)a*CC + lbl] * (o2 * o2 * o2);
    if (val > v[TOPK-1] || (val == v[TOPK-1] && a < id[TOPK-1])) {
      #pragma unroll
      for (int i = TOPK-1; i >= 1; --i) {   // static-index shift network
        const bool ci = (val > v[i])   || (val == v[i]   && a < id[i]);
        const bool cp = (val > v[i-1]) || (val == v[i-1] && a < id[i-1]);
        if (ci) {
          if (cp) { v[i] = v[i-1]; id[i] = id[i-1]; }
          else    { v[i] = val;    id[i] = a; }
        }
      }
      if (val > v[0] || (val == v[0] && a < id[0])) { v[0] = val; id[0] = a; }
    }
  }

  // per-wave 13-round extraction (val desc, idx asc) -> LDS
  for (int r = 0; r < TOPK; ++r) {
    float bv = v[0]; int bi = id[0];
    #pragma unroll
    for (int off = 32; off; off >>= 1) {
      const float ovv = __shfl_xor(bv, off);
      const int   oii = __shfl_xor(bi, off);
      if (ovv > bv || (ovv == bv && oii < bi)) { bv = ovv; bi = oii; }
    }
    if (v[0] == bv && id[0] == bi) {        // unique winner pops its head
      #pragma unroll
      for (int i = 0; i < TOPK-1; ++i) { v[i] = v[i+1]; id[i] = id[i+1]; }
      v[TOPK-1] = -1.f; id[TOPK-1] = 0x7fffffff;
    }
    if (lane == 0) s_top[wave][r] = make_uint2(__float_as_uint(bv), (unsigned)bi);
  }
  __syncthreads();
  if (wave != 0) return;

  // wave-0 merge of 4x13 entries; in-gts flags prefetched in parallel
  float mv = -1.f; int mi = 0x7fffffff; bool ing = false;
  if (lane < NW*TOPK) {
    const uint2 c = s_top[lane/TOPK][lane%TOPK];
    mv = __uint_as_float(c.x); mi = (int)c.y;
    if (mi < AA) {
      const float2 xy = axy[mi];
      const float mind = fminf(fminf(xy.x - gb.x, xy.y - gb.y),
                               fminf(gb.z - xy.x, gb.w - xy.y));
      ing = mind > 1e-9f;
    }
  }
  const unsigned int bit = 1u << m;
  for (int r = 0; r < TOPK; ++r) {
    float bv = mv; int bi = mi;
    #pragma unroll
    for (int off = 32; off; off >>= 1) {
      const float ovv = __shfl_xor(bv, off);
      const int   oii = __shfl_xor(bi, off);
      if (ovv > bv || (ovv == bv && oii < bi)) { bv = ovv; bi = oii; }
    }
    const bool win = (mv == bv) && (mi == bi);   // unique for real entries;
    if (win && ing) atomicOr(&claim[b*AA + bi], bit);  // sentinels have ing=false
    if (win) { mv = -1.f; mi = 0x7fffffff; ing = false; }
  }
}

// ---------------------------------------------------------------------------
// K2: per-anchor resolution with sparse CIoU recompute. fg==1 -> claiming m;
// fg>1 -> first-max argmax_m of masked overlaps (recomputed). Writes
// target_bbox + fg_mask + anchor_m/al; atomicMax pos_align/pos_ovl.
// ---------------------------------------------------------------------------
__global__ __launch_bounds__(256) void k_resolve(
    const float* __restrict__ pred_cls, const float* __restrict__ pred_bbox,
    const float* __restrict__ anchors, const int* __restrict__ gt_cls,
    const float* __restrict__ gt_bbox, const float* __restrict__ mask_gt,
    const unsigned int* __restrict__ claim,
    float* __restrict__ out_bbox, float* __restrict__ out_fg,
    int* __restrict__ anchor_m, float* __restrict__ anchor_al,
    unsigned int* __restrict__ pos_align, unsigned int* __restrict__ pos_ovl)
{
  const int b = blockIdx.y;
  __shared__ float s_x1[MM], s_y1[MM], s_x2[MM], s_y2[MM], s_at[MM], s_mgt[MM];
  __shared__ int s_lbl[MM];
  if (threadIdx.x < MM) {
    int m = threadIdx.x;
    float4 g = reinterpret_cast<const float4*>(gt_bbox)[b*MM + m];
    s_x1[m] = g.x; s_y1[m] = g.y; s_x2[m] = g.z; s_y2[m] = g.w;
    s_at[m] = atanf((g.z - g.x) / (g.w - g.y + 1e-7f));
    s_lbl[m] = gt_cls[b*MM + m];
    s_mgt[m] = mask_gt[b*MM + m];
  }
  __syncthreads();
  const int a = blockIdx.x*256 + threadIdx.x;
  if (a >= AA) return;
  const unsigned int cb = claim[b*AA + a];
  const int fg = __popc(cb);
  int asg = -1; float bestov = 0.f;
  if (fg > 0) {
    const float4 pb = reinterpret_cast<const float4*>(pred_bbox)[b*AA + a];
    const float2 xy = reinterpret_cast<const float2*>(anchors)[a];
    const float w2 = pb.z - pb.x, h2 = pb.w - pb.y + 1e-7f;
    const float at2 = atanf(w2 / h2);
    if (fg == 1) {
      asg = __ffs(cb) - 1;   // claimed => in-gts && mask_gt>0 already hold
      bestov = ciou_clip(s_x1[asg], s_y1[asg], s_x2[asg], s_y2[asg], s_at[asg],
                         pb, w2, h2, at2);
    } else {
      // is_max: first argmax over ALL m of masked overlaps
      float best = -1.f; int bm = 0;
      for (int m = 0; m < MM; ++m) {
        float ov = 0.f;
        const float mind = fminf(fminf(xy.x - s_x1[m], xy.y - s_y1[m]),
                                 fminf(s_x2[m] - xy.x, s_y2[m] - xy.y));
        if (mind > 1e-9f && s_mgt[m] > 0.f)
          ov = ciou_clip(s_x1[m], s_y1[m], s_x2[m], s_y2[m], s_at[m],
                         pb, w2, h2, at2);
        if (ov > best) { best = ov; bm = m; }   // strict > => first max
      }
      asg = bm; bestov = best;
    }
  }
  const int tgt = (asg >= 0) ? asg : 0;   // argmax of all-zero column = 0
  float4 tb; tb.x = s_x1[tgt]; tb.y = s_y1[tgt]; tb.z = s_x2[tgt]; tb.w = s_y2[tgt];
  reinterpret_cast<float4*>(out_bbox)[b*AA + a] = tb;
  out_fg[b*AA + a] = (asg >= 0) ? 1.f : 0.f;
  anchor_m[b*AA + a] = asg;
  float av = 0.f;
  if (asg >= 0) {
    const float o2 = bestov * bestov;
    av = pred_cls[(size_t)(b*AA + a)*CC + s_lbl[asg]] * (o2 * o2 * o2);
    atomicMax(&pos_align[b*MM + asg], __float_as_uint(av));    // >=0 floats
    atomicMax(&pos_ovl[b*MM + asg], __float_as_uint(bestov));
  }
  anchor_al[b*AA + a] = av;
}

// ---------------------------------------------------------------------------
// K3: target_cls (B,A,C) float4-coalesced: norm at the label slot, else 0.
// ---------------------------------------------------------------------------
__global__ __launch_bounds__(256) void k_cls(
    const int* __restrict__ anchor_m, const float* __restrict__ anchor_al,
    const unsigned int* __restrict__ pos_align, const unsigned int* __restrict__ pos_ovl,
    const int* __restrict__ gt_cls, float* __restrict__ out_cls)
{
  const int tid = blockIdx.x*256 + threadIdx.x;
  if (tid >= BB*AA*(CC/4)) return;
  const int q  = tid % (CC/4);
  const int ba = tid / (CC/4);
  const int b  = ba / AA;
  const int m  = anchor_m[ba];
  float4 o = make_float4(0.f, 0.f, 0.f, 0.f);
  if (m >= 0) {
    const float pa = __uint_as_float(pos_align[b*MM + m]);
    const float po = __uint_as_float(pos_ovl[b*MM + m]);
    const float norm = anchor_al[ba] * po / (pa + 1e-9f);
    const int lbl = gt_cls[b*MM + m];
    const int c0 = q * 4;
    if (lbl == c0    ) o.x = norm;
    if (lbl == c0 + 1) o.y = norm;
    if (lbl == c0 + 2) o.z = norm;
    if (lbl == c0 + 3) o.w = norm;
  }
  reinterpret_cast<float4*>(out_cls)[tid] = o;
}

// ---------------------------------------------------------------------------
extern "C" void kernel_launch(void* const* d_in, const int* in_sizes, int n_in,
                              void* d_out, int out_size, void* d_ws, size_t ws_size,
                              hipStream_t stream)
{
  const float* pred_cls  = (const float*)d_in[0];
  const float* pred_bbox = (const float*)d_in[1];
  const float* anchors   = (const float*)d_in[2];
  const int*   gt_cls    = (const int*)  d_in[3];
  const float* gt_bbox   = (const float*)d_in[4];
  const float* mask_gt   = (const float*)d_in[5];

  // ws layout:
  //   claim      : B*A u32             @ 0          (537600 B)
  //   pos_align  : B*M u32(float)      @ 537600     (2048 B)
  //   pos_ovl    : B*M u32(float)      @ 539648     (2048 B)
  //   anchor_m   : B*A i32             @ 541696     (537600 B)
  //   anchor_al  : B*A f32             @ 1079296    (537600 B)
  //   inmaskT    : B*M*264 u32         @ 1616896    (540672 B)
  // total 2157568 B (~2.1 MB)
  char* ws = (char*)d_ws;
  unsigned int* claim     = (unsigned int*)(ws);
  unsigned int* pos_align = (unsigned int*)(ws + 537600);
  unsigned int* pos_ovl   = (unsigned int*)(ws + 539648);
  int*   anchor_m  = (int*)  (ws + 541696);
  float* anchor_al = (float*)(ws + 1079296);
  unsigned int* inmaskT = (unsigned int*)(ws + 1616896);

  float* out_cls  = (float*)d_out;
  float* out_bbox = out_cls + (size_t)BB*AA*CC;
  float* out_fg   = out_bbox + (size_t)BB*AA*4;

  k_mask<<<dim3(33, BB), 256, 0, stream>>>(
      anchors, gt_bbox, mask_gt, inmaskT, claim, pos_align, pos_ovl);
  k_topk<<<dim3(MM, BB), 256, 0, stream>>>(
      pred_cls, pred_bbox, anchors, gt_cls, gt_bbox, mask_gt, inmaskT, claim);
  k_resolve<<<dim3((AA + 255)/256, BB), 256, 0, stream>>>(
      pred_cls, pred_bbox, anchors, gt_cls, gt_bbox, mask_gt, claim,
      out_bbox, out_fg, anchor_m, anchor_al, pos_align, pos_ovl);
  k_cls<<<(BB*AA*(CC/4) + 255)/256, 256, 0, stream>>>(
      anchor_m, anchor_al, pos_align, pos_ovl, gt_cls, out_cls);
}

// Round 11
// 50.006 us; speedup vs baseline: 1.7191x; 1.1146x over previous
//
#include <hip/hip_runtime.h>
#include <cstdint>
#include <cstddef>

#define BB 16
#define AA 8400
#define CC 80
#define MM 32
#define TOPK 13
#define NW 8                 // waves (chunks) per row-block
#define WORDS 264            // u32 words per (b,m) row (8448 bits >= AA)
#define CWORDS 33            // words per chunk
#define CANCH (CWORDS * 32)  // 1056 anchors per chunk

// Shared CIoU (clipped) so every use site has the identical formula.
__device__ __forceinline__ float ciou_clip(
    float gx1, float gy1, float gx2, float gy2, float at1,
    float4 pb, float w2, float h2, float at2)
{
  const float w1 = gx2 - gx1, h1 = gy2 - gy1 + 1e-7f;
  const float iw = fmaxf(fminf(gx2, pb.z) - fmaxf(gx1, pb.x), 0.f);
  const float ih = fmaxf(fminf(gy2, pb.w) - fmaxf(gy1, pb.y), 0.f);
  const float inter = iw * ih;
  const float uni = w1*h1 + w2*h2 - inter + 1e-7f;
  const float iou = inter / uni;
  const float cw = fmaxf(gx2, pb.z) - fminf(gx1, pb.x);
  const float ch = fmaxf(gy2, pb.w) - fminf(gy1, pb.y);
  const float c2 = cw*cw + ch*ch + 1e-7f;
  const float rx = pb.x + pb.z - gx1 - gx2;
  const float ry = pb.y + pb.w - gy1 - gy2;
  const float rho2 = (rx*rx + ry*ry) * 0.25f;
  const float dv = at2 - at1;
  const float v = 0.4052847345693511f * dv * dv;
  const float alpha = v / (v - iou + (1.f + 1e-7f));
  return fmaxf(iou - (rho2 / c2 + v * alpha), 0.f);
}

// (val desc, idx asc) as one monotone u64 key; val >= 0 so float bits are
// order-preserving. Sentinel/empty = 0 (loses to every real entry; decodes
// to anchor -1 — ALL decode sites must use unsigned bounds checks).
__device__ __forceinline__ unsigned long long pack_key(float val, int a) {
  return ((unsigned long long)__float_as_uint(val) << 32)
       | (unsigned long long)(0xFFFFFFFFu - (unsigned)a);
}
__device__ __forceinline__ int key_anchor(unsigned long long k) {
  return (int)(0xFFFFFFFFu - (unsigned)(k & 0xFFFFFFFFull));
}

// ---------------------------------------------------------------------------
// K0: transposed in-gts bitmask via per-m ballots (atomic-free), plus
// claim/pos_* zero-init. Thread (b,a); wave covers 64 consecutive a = 2 words.
// Masked gts are poisoned so their rows come out all-zero.
// ---------------------------------------------------------------------------
__global__ __launch_bounds__(256) void k_mask(
    const float* __restrict__ anchors, const float* __restrict__ gt_bbox,
    const float* __restrict__ mask_gt, unsigned int* __restrict__ inmaskT,
    unsigned int* __restrict__ claim,
    unsigned int* __restrict__ pos_align, unsigned int* __restrict__ pos_ovl)
{
  const int b = blockIdx.y;
  __shared__ float4 s_mb[MM];
  if (threadIdx.x < MM) {
    const int m = threadIdx.x;
    const float4 g = reinterpret_cast<const float4*>(gt_bbox)[b*MM + m];
    s_mb[m] = (mask_gt[b*MM + m] > 0.f) ? g
              : make_float4(1e30f, 1e30f, -1e30f, -1e30f);
    if (blockIdx.x == 0) { pos_align[b*MM + m] = 0u; pos_ovl[b*MM + m] = 0u; }
  }
  __syncthreads();
  const int a = blockIdx.x*256 + threadIdx.x;
  const int wave = threadIdx.x >> 6, lane = threadIdx.x & 63;
  float2 xy = make_float2(-1e30f, -1e30f);      // a>=AA lanes: always fail
  if (a < AA) {
    xy = reinterpret_cast<const float2*>(anchors)[a];
    claim[b*AA + a] = 0u;                       // zero-init (replaces memset)
  }
  const int wslot = blockIdx.x*8 + wave*2;      // first of this wave's 2 words
  #pragma unroll
  for (int m = 0; m < MM; ++m) {
    const float4 g = s_mb[m];
    const float mind = fminf(fminf(xy.x - g.x, xy.y - g.y),
                             fminf(g.z - xy.x, g.w - xy.y));
    const unsigned long long bal = __ballot(mind > 1e-9f);
    unsigned int* wp = inmaskT + (size_t)(b*MM + m)*WORDS + wslot;
    if (lane == 0) wp[0] = (unsigned int)(bal & 0xffffffffull);
    if (lane == 1) wp[1] = (unsigned int)(bal >> 32);
  }
}

// ---------------------------------------------------------------------------
// K1: one block per (b,m) row; 8 waves, each owns a 33-word (1056-anchor)
// chunk: bit-scan -> LDS queue, dense CIoU eval of queue only, per-lane
// top-13 as u64 keys, 13-round butterfly per wave -> LDS, wave-0 merge of
// 8x13 (2 slots/lane) -> exact row top-13 -> in-gts check + claim atomicOr.
// Zero-tie fill exactness: wave 0 seeds anchors [0,64) with full evals
// (val==0 when out-of-gts) and zeroes queue words 0-1 (covered by seed);
// a row with <13 positives zero-fills from indices <64 (>=51 zeros there),
// ties resolved by ascending index — matches jax.lax.top_k exactly.
// ---------------------------------------------------------------------------
__global__ __launch_bounds__(512) void k_topk(
    const float* __restrict__ pred_cls, const float* __restrict__ pred_bbox,
    const float* __restrict__ anchors, const int* __restrict__ gt_cls,
    const float* __restrict__ gt_bbox, const float* __restrict__ mask_gt,
    const unsigned int* __restrict__ inmaskT, unsigned int* __restrict__ claim)
{
  const int m = blockIdx.x, b = blockIdx.y;
  if (mask_gt[b*MM + m] <= 0.f) return;   // uniform per block
  const int wave = threadIdx.x >> 6, lane = threadIdx.x & 63;
  __shared__ unsigned short q[NW][CANCH];
  __shared__ unsigned long long s_top[NW][TOPK];

  const float4 gb = reinterpret_cast<const float4*>(gt_bbox)[b*MM + m];
  const float at1 = atanf((gb.z - gb.x) / (gb.w - gb.y + 1e-7f));
  const int lbl = gt_cls[b*MM + m];
  const float*  clsbase = pred_cls + (size_t)b*AA*CC;
  const float4* pbase   = reinterpret_cast<const float4*>(pred_bbox) + (size_t)b*AA;
  const float2* axy     = reinterpret_cast<const float2*>(anchors);

  unsigned long long k13[TOPK];
  #pragma unroll
  for (int i = 0; i < TOPK; ++i) k13[i] = 0ull;

  // wave-0 seed: full eval of anchor a = lane (always a candidate)
  if (wave == 0) {
    const int a = lane;
    const float2 xy = axy[a];
    const float mind = fminf(fminf(xy.x - gb.x, xy.y - gb.y),
                             fminf(gb.z - xy.x, gb.w - xy.y));
    float val = 0.f;
    if (mind > 1e-9f) {
      const float4 pb = pbase[a];
      const float w2 = pb.z - pb.x, h2 = pb.w - pb.y + 1e-7f;
      const float at2 = atanf(w2 / h2);
      const float ov = ciou_clip(gb.x, gb.y, gb.z, gb.w, at1, pb, w2, h2, at2);
      const float o2 = ov * ov;
      val = clsbase[(size_t)a*CC + lbl] * (o2 * o2 * o2);
    }
    k13[0] = pack_key(val, a);
  }

  // bit-scan chunk (single 33-word pass) -> queue, ascending anchor order
  const unsigned int* wrow = inmaskT + (size_t)(b*MM + m)*WORDS + wave*CWORDS;
  unsigned int w = 0u;
  if (lane < CWORDS) w = wrow[lane];
  if (wave == 0 && lane < 2) w = 0u;        // a<64 covered by seed
  const int cnt = __popc(w);
  int incl = cnt;
  #pragma unroll
  for (int off = 1; off < 64; off <<= 1) {
    const int t = __shfl_up(incl, off);
    if (lane >= off) incl += t;
  }
  int pos = incl - cnt;
  {
    const int lbase = lane*32;                // local anchor base in chunk
    unsigned int t = w;
    while (t) {
      const int bit = __ffs((int)t) - 1; t &= t - 1u;
      q[wave][pos++] = (unsigned short)(lbase + bit);
    }
  }
  const int qc = __shfl(incl, 63);

  // dense eval of queue (per-lane stream ascending in a; key compare exact)
  const int abase = wave * CANCH;
  for (int k = lane; k < qc; k += 64) {
    const int a = abase + (int)q[wave][k];
    const float4 pb = pbase[a];
    const float w2 = pb.z - pb.x, h2 = pb.w - pb.y + 1e-7f;
    const float at2 = atanf(w2 / h2);
    const float ov = ciou_clip(gb.x, gb.y, gb.z, gb.w, at1, pb, w2, h2, at2);
    const float o2 = ov * ov;
    const float val = clsbase[(size_t)a*CC + lbl] * (o2 * o2 * o2);
    const unsigned long long key = pack_key(val, a);
    if (key > k13[TOPK-1]) {
      #pragma unroll
      for (int i = TOPK-1; i >= 1; --i)       // static-index shift network
        if (key > k13[i]) k13[i] = (key > k13[i-1]) ? k13[i-1] : key;
      if (key > k13[0]) k13[0] = key;
    }
  }

  // per-wave 13-round extraction (u64 butterfly max) -> LDS
  for (int r = 0; r < TOPK; ++r) {
    unsigned long long bk = k13[0];
    #pragma unroll
    for (int off = 32; off; off >>= 1) {
      const unsigned long long o = __shfl_xor(bk, off);
      if (o > bk) bk = o;
    }
    if (k13[0] == bk) {                       // unique for real keys;
      #pragma unroll                          // sentinel multi-pop harmless
      for (int i = 0; i < TOPK-1; ++i) k13[i] = k13[i+1];
      k13[TOPK-1] = 0ull;
    }
    if (lane == 0) s_top[wave][r] = bk;
  }
  __syncthreads();
  if (wave != 0) return;

  // wave-0 merge of 8x13 = 104 keys: 2 static slots/lane; in-gts prefetched.
  // NOTE: sentinel keys decode to anchor -1 -> UNSIGNED bounds checks only.
  unsigned long long v0 = 0ull, v1 = 0ull;
  bool g0 = false, g1 = false;
  {
    const int e0 = lane, e1 = lane + 64;
    v0 = s_top[e0/TOPK][e0%TOPK];
    if (e1 < NW*TOPK) v1 = s_top[e1/TOPK][e1%TOPK];
    const int a0 = key_anchor(v0), a1 = key_anchor(v1);
    if ((unsigned)a0 < (unsigned)AA) {        // rejects sentinel (-1)
      const float2 xy = axy[a0];
      g0 = fminf(fminf(xy.x - gb.x, xy.y - gb.y),
                 fminf(gb.z - xy.x, gb.w - xy.y)) > 1e-9f;
    }
    if ((unsigned)a1 < (unsigned)AA) {        // rejects sentinel (-1)
      const float2 xy = axy[a1];
      g1 = fminf(fminf(xy.x - gb.x, xy.y - gb.y),
                 fminf(gb.z - xy.x, gb.w - xy.y)) > 1e-9f;
    }
  }
  const unsigned int bit = 1u << m;
  for (int r = 0; r < TOPK; ++r) {
    const bool s1 = v1 > v0;
    unsigned long long bk = s1 ? v1 : v0;
    const unsigned long long my = bk;
    #pragma unroll
    for (int off = 32; off; off >>= 1) {
      const unsigned long long o = __shfl_xor(bk, off);
      if (o > bk) bk = o;
    }
    if (my == bk && bk != 0ull) {             // unique winner (real key)
      const bool ing = s1 ? g1 : g0;
      if (ing) atomicOr(&claim[b*AA + key_anchor(bk)], bit);
      if (s1) { v1 = 0ull; g1 = false; } else { v0 = 0ull; g0 = false; }
    }
  }
}

// ---------------------------------------------------------------------------
// K2: per-anchor resolution with sparse CIoU recompute. fg==1 -> claiming m;
// fg>1 -> first-max argmax_m of masked overlaps (recomputed). Writes
// target_bbox + fg_mask + anchor_m/al; atomicMax pos_align/pos_ovl.
// ---------------------------------------------------------------------------
__global__ __launch_bounds__(256) void k_resolve(
    const float* __restrict__ pred_cls, const float* __restrict__ pred_bbox,
    const float* __restrict__ anchors, const int* __restrict__ gt_cls,
    const float* __restrict__ gt_bbox, const float* __restrict__ mask_gt,
    const unsigned int* __restrict__ claim,
    float* __restrict__ out_bbox, float* __restrict__ out_fg,
    int* __restrict__ anchor_m, float* __restrict__ anchor_al,
    unsigned int* __restrict__ pos_align, unsigned int* __restrict__ pos_ovl)
{
  const int b = blockIdx.y;
  __shared__ float s_x1[MM], s_y1[MM], s_x2[MM], s_y2[MM], s_at[MM], s_mgt[MM];
  __shared__ int s_lbl[MM];
  if (threadIdx.x < MM) {
    int m = threadIdx.x;
    float4 g = reinterpret_cast<const float4*>(gt_bbox)[b*MM + m];
    s_x1[m] = g.x; s_y1[m] = g.y; s_x2[m] = g.z; s_y2[m] = g.w;
    s_at[m] = atanf((g.z - g.x) / (g.w - g.y + 1e-7f));
    s_lbl[m] = gt_cls[b*MM + m];
    s_mgt[m] = mask_gt[b*MM + m];
  }
  __syncthreads();
  const int a = blockIdx.x*256 + threadIdx.x;
  if (a >= AA) return;
  const unsigned int cb = claim[b*AA + a];
  const int fg = __popc(cb);
  int asg = -1; float bestov = 0.f;
  if (fg > 0) {
    const float4 pb = reinterpret_cast<const float4*>(pred_bbox)[b*AA + a];
    const float2 xy = reinterpret_cast<const float2*>(anchors)[a];
    const float w2 = pb.z - pb.x, h2 = pb.w - pb.y + 1e-7f;
    const float at2 = atanf(w2 / h2);
    if (fg == 1) {
      asg = __ffs(cb) - 1;   // claimed => in-gts && mask_gt>0 already hold
      bestov = ciou_clip(s_x1[asg], s_y1[asg], s_x2[asg], s_y2[asg], s_at[asg],
                         pb, w2, h2, at2);
    } else {
      // is_max: first argmax over ALL m of masked overlaps
      float best = -1.f; int bm = 0;
      for (int m = 0; m < MM; ++m) {
        float ov = 0.f;
        const float mind = fminf(fminf(xy.x - s_x1[m], xy.y - s_y1[m]),
                                 fminf(s_x2[m] - xy.x, s_y2[m] - xy.y));
        if (mind > 1e-9f && s_mgt[m] > 0.f)
          ov = ciou_clip(s_x1[m], s_y1[m], s_x2[m], s_y2[m], s_at[m],
                         pb, w2, h2, at2);
        if (ov > best) { best = ov; bm = m; }   // strict > => first max
      }
      asg = bm; bestov = best;
    }
  }
  const int tgt = (asg >= 0) ? asg : 0;   // argmax of all-zero column = 0
  float4 tb; tb.x = s_x1[tgt]; tb.y = s_y1[tgt]; tb.z = s_x2[tgt]; tb.w = s_y2[tgt];
  reinterpret_cast<float4*>(out_bbox)[b*AA + a] = tb;
  out_fg[b*AA + a] = (asg >= 0) ? 1.f : 0.f;
  anchor_m[b*AA + a] = asg;
  float av = 0.f;
  if (asg >= 0) {
    const float o2 = bestov * bestov;
    av = pred_cls[(size_t)(b*AA + a)*CC + s_lbl[asg]] * (o2 * o2 * o2);
    atomicMax(&pos_align[b*MM + asg], __float_as_uint(av));    // >=0 floats
    atomicMax(&pos_ovl[b*MM + asg], __float_as_uint(bestov));
  }
  anchor_al[b*AA + a] = av;
}

// ---------------------------------------------------------------------------
// K3: target_cls (B,A,C) float4-coalesced: norm at the label slot, else 0.
// ---------------------------------------------------------------------------
__global__ __launch_bounds__(256) void k_cls(
    const int* __restrict__ anchor_m, const float* __restrict__ anchor_al,
    const unsigned int* __restrict__ pos_align, const unsigned int* __restrict__ pos_ovl,
    const int* __restrict__ gt_cls, float* __restrict__ out_cls)
{
  const int tid = blockIdx.x*256 + threadIdx.x;
  if (tid >= BB*AA*(CC/4)) return;
  const int q  = tid % (CC/4);
  const int ba = tid / (CC/4);
  const int b  = ba / AA;
  const int m  = anchor_m[ba];
  float4 o = make_float4(0.f, 0.f, 0.f, 0.f);
  if (m >= 0) {
    const float pa = __uint_as_float(pos_align[b*MM + m]);
    const float po = __uint_as_float(pos_ovl[b*MM + m]);
    const float norm = anchor_al[ba] * po / (pa + 1e-9f);
    const int lbl = gt_cls[b*MM + m];
    const int c0 = q * 4;
    if (lbl == c0    ) o.x = norm;
    if (lbl == c0 + 1) o.y = norm;
    if (lbl == c0 + 2) o.z = norm;
    if (lbl == c0 + 3) o.w = norm;
  }
  reinterpret_cast<float4*>(out_cls)[tid] = o;
}

// ---------------------------------------------------------------------------
extern "C" void kernel_launch(void* const* d_in, const int* in_sizes, int n_in,
                              void* d_out, int out_size, void* d_ws, size_t ws_size,
                              hipStream_t stream)
{
  const float* pred_cls  = (const float*)d_in[0];
  const float* pred_bbox = (const float*)d_in[1];
  const float* anchors   = (const float*)d_in[2];
  const int*   gt_cls    = (const int*)  d_in[3];
  const float* gt_bbox   = (const float*)d_in[4];
  const float* mask_gt   = (const float*)d_in[5];

  // ws layout:
  //   claim      : B*A u32             @ 0          (537600 B)
  //   pos_align  : B*M u32(float)      @ 537600     (2048 B)
  //   pos_ovl    : B*M u32(float)      @ 539648     (2048 B)
  //   anchor_m   : B*A i32             @ 541696     (537600 B)
  //   anchor_al  : B*A f32             @ 1079296    (537600 B)
  //   inmaskT    : B*M*264 u32         @ 1616896    (540672 B)
  // total 2157568 B (~2.1 MB)
  char* ws = (char*)d_ws;
  unsigned int* claim     = (unsigned int*)(ws);
  unsigned int* pos_align = (unsigned int*)(ws + 537600);
  unsigned int* pos_ovl   = (unsigned int*)(ws + 539648);
  int*   anchor_m  = (int*)  (ws + 541696);
  float* anchor_al = (float*)(ws + 1079296);
  unsigned int* inmaskT = (unsigned int*)(ws + 1616896);

  float* out_cls  = (float*)d_out;
  float* out_bbox = out_cls + (size_t)BB*AA*CC;
  float* out_fg   = out_bbox + (size_t)BB*AA*4;

  k_mask<<<dim3(33, BB), 256, 0, stream>>>(
      anchors, gt_bbox, mask_gt, inmaskT, claim, pos_align, pos_ovl);
  k_topk<<<dim3(MM, BB), 512, 0, stream>>>(
      pred_cls, pred_bbox, anchors, gt_cls, gt_bbox, mask_gt, inmaskT, claim);
  k_resolve<<<dim3((AA + 255)/256, BB), 256, 0, stream>>>(
      pred_cls, pred_bbox, anchors, gt_cls, gt_bbox, mask_gt, claim,
      out_bbox, out_fg, anchor_m, anchor_al, pos_align, pos_ovl);
  k_cls<<<(BB*AA*(CC/4) + 255)/256, 256, 0, stream>>>(
      anchor_m, anchor_al, pos_align, pos_ovl, gt_cls, out_cls);
}